// Round 1
// baseline (149.937 us; speedup 1.0000x reference)
//
#include <hip/hip_runtime.h>
#include <hip/hip_bf16.h>

// Problem constants (from reference)
#define BB 1024
#define SS 200
#define PQ_M 8
#define VALS 256
#define SUB_DIM 16
#define N_TOKENS (BB * SS)            // 204800
#define OUT_PER_TOKEN (PQ_M * SUB_DIM) // 128 floats = 512 B

// 32 threads per token; thread t writes float4 #t of the token's 512B output.
// m = t>>2 (PQ dim), sub-chunk = t&3. Wave64 = exactly 2 tokens, stores fully
// coalesced (lane i -> token_base + i*16B, contiguous 1KB per wave store).
__global__ __launch_bounds__(256) void pq_gather_kernel(
    const int*   __restrict__ ids,      // [N_TOKENS] item ids (int32)
    const int*   __restrict__ codes,    // [(NUM_ITEMS+2) * PQ_M] byte codes
    const float* __restrict__ cent,     // [PQ_M * VALS * SUB_DIM] fp32
    float*       __restrict__ out)      // [N_TOKENS * 128] fp32
{
    const int tid   = blockIdx.x * blockDim.x + threadIdx.x;
    const int token = tid >> 5;        // 32 threads per token
    const int t     = tid & 31;
    if (token >= N_TOKENS) return;

    const int id   = ids[token];                 // broadcast across 32 lanes (cached)
    const int m    = t >> 2;                     // PQ dim 0..7
    const int code = codes[id * PQ_M + m];       // one 64B line per token

    // centroids[m][code][0..15], take float4 chunk (t&3); 4 lanes broadcast-read
    const float4* src =
        (const float4*)(cent + ((size_t)(m * VALS + code) * SUB_DIM));
    const float4 v = src[t & 3];

    float4* dst = (float4*)(out + (size_t)token * OUT_PER_TOKEN);
    dst[t] = v;
}

extern "C" void kernel_launch(void* const* d_in, const int* in_sizes, int n_in,
                              void* d_out, int out_size, void* d_ws, size_t ws_size,
                              hipStream_t stream)
{
    const int*   ids   = (const int*)d_in[0];    // input_ids [1024,200] (int)
    const int*   codes = (const int*)d_in[1];    // item_codes [1000002,8]
    const float* cent  = (const float*)d_in[2];  // centroids [8,256,16] fp32
    float*       out   = (float*)d_out;          // [1024,200,128] fp32

    const int total_threads = N_TOKENS * 32;     // 6,553,600
    const int block = 256;
    const int grid  = (total_threads + block - 1) / block;  // 25600
    pq_gather_kernel<<<grid, block, 0, stream>>>(ids, codes, cent, out);
}

// Round 2
// 144.368 us; speedup vs baseline: 1.0386x; 1.0386x over previous
//
#include <hip/hip_runtime.h>
#include <hip/hip_bf16.h>

// Problem constants (from reference)
#define BB 1024
#define SS 200
#define PQ_M 8
#define VALS 256
#define SUB_DIM 16
#define N_TOKENS (BB * SS)             // 204800
#define OUT_PER_TOKEN (PQ_M * SUB_DIM) // 128 floats = 512 B

#define T_PER_THREAD 4
#define TOK_SLICE (N_TOKENS / T_PER_THREAD)  // 51200

// 32 threads per token-slot; each thread services T_PER_THREAD=4 tokens
// (slot, slot+51200, ...) with INDEPENDENT load chains to get 4x memory-level
// parallelism per wave. Within each token: thread t writes float4 #t of the
// token's 512B output; m = t>>2 selects the PQ dim, t&3 the 16B sub-chunk.
// Stores per iteration are fully coalesced (wave = 2 consecutive tokens,
// contiguous 1KB).
__global__ __launch_bounds__(256) void pq_gather_kernel(
    const int*   __restrict__ ids,      // [N_TOKENS] item ids (int32)
    const int*   __restrict__ codes,    // [(NUM_ITEMS+2) * PQ_M] byte codes
    const float* __restrict__ cent,     // [PQ_M * VALS * SUB_DIM] fp32
    float*       __restrict__ out)      // [N_TOKENS * 128] fp32
{
    const int gid  = blockIdx.x * blockDim.x + threadIdx.x;
    const int t    = gid & 31;          // 0..31 within token
    const int slot = gid >> 5;          // 0..TOK_SLICE-1
    const int m    = t >> 2;            // PQ dim 0..7
    const int c4   = t & 3;             // float4 chunk within sub-vector

    int tok[T_PER_THREAD];
#pragma unroll
    for (int j = 0; j < T_PER_THREAD; ++j)
        tok[j] = slot + j * TOK_SLICE;

    // Stage 1: 4 independent id loads (one vmcnt batch)
    int id[T_PER_THREAD];
#pragma unroll
    for (int j = 0; j < T_PER_THREAD; ++j)
        id[j] = ids[tok[j]];

    // Stage 2: 4 independent random code gathers (the HBM-latency stage)
    int code[T_PER_THREAD];
#pragma unroll
    for (int j = 0; j < T_PER_THREAD; ++j)
        code[j] = codes[id[j] * PQ_M + m];

    // Stage 3: 4 independent centroid float4 reads (L2-resident 128KB table)
    float4 v[T_PER_THREAD];
    const float4* cent4 = (const float4*)cent;
#pragma unroll
    for (int j = 0; j < T_PER_THREAD; ++j)
        v[j] = cent4[(m * VALS + code[j]) * (SUB_DIM / 4) + c4];

    // Stage 4: 4 coalesced float4 stores
#pragma unroll
    for (int j = 0; j < T_PER_THREAD; ++j)
        ((float4*)(out + (size_t)tok[j] * OUT_PER_TOKEN))[t] = v[j];
}

extern "C" void kernel_launch(void* const* d_in, const int* in_sizes, int n_in,
                              void* d_out, int out_size, void* d_ws, size_t ws_size,
                              hipStream_t stream)
{
    const int*   ids   = (const int*)d_in[0];    // input_ids [1024,200]
    const int*   codes = (const int*)d_in[1];    // item_codes [1000002,8]
    const float* cent  = (const float*)d_in[2];  // centroids [8,256,16] fp32
    float*       out   = (float*)d_out;          // [1024,200,128] fp32

    const int total_threads = (N_TOKENS / T_PER_THREAD) * 32;  // 1,638,400
    const int block = 256;
    const int grid  = total_threads / block;                   // 6400
    pq_gather_kernel<<<grid, block, 0, stream>>>(ids, codes, cent, out);
}